// Round 3
// baseline (481.981 us; speedup 1.0000x reference)
//
#include <hip/hip_runtime.h>
#include <hip/hip_bf16.h>
#include <stdint.h>

#define DIM 512

typedef short short8 __attribute__((ext_vector_type(8)));
typedef float floatx4 __attribute__((ext_vector_type(4)));

// f32 -> bf16 round-to-nearest-even
__device__ inline unsigned short f2b(float x){
  uint32_t u = __float_as_uint(x);
  u += 0x7FFFu + ((u >> 16) & 1u);
  return (unsigned short)(u >> 16);
}
__device__ inline float blo(uint32_t u){ return __uint_as_float(u << 16); }
__device__ inline float bhi(uint32_t u){ return __uint_as_float(u & 0xFFFF0000u); }

// ---------------- CSR build ----------------
__global__ void k_count(const int* __restrict__ ei, int* __restrict__ cnt, int E){
  int e = blockIdx.x * blockDim.x + threadIdx.x;
  if (e < E) atomicAdd(&cnt[ei[E + e]], 1);
}

// ---- hierarchical exclusive scan of cnt[0..n) -> rowptr[0..n], 1024 elems/block ----
__global__ __launch_bounds__(256)
void k_bsum(const int* __restrict__ cnt, int* __restrict__ partial, int n){
  __shared__ int sh[4];
  int t = threadIdx.x;
  int base = blockIdx.x * 1024 + t * 4;
  int s = 0;
  if (base + 3 < n){
    int4 v = *(const int4*)(cnt + base);
    s = v.x + v.y + v.z + v.w;
  } else {
    for (int j = 0; j < 4; ++j) if (base + j < n) s += cnt[base + j];
  }
  for (int d = 32; d; d >>= 1) s += __shfl_down(s, d);
  if ((t & 63) == 0) sh[t >> 6] = s;
  __syncthreads();
  if (t == 0) partial[blockIdx.x] = sh[0] + sh[1] + sh[2] + sh[3];
}

__global__ void k_pscan(int* __restrict__ partial, int* __restrict__ rowptr, int nb, int n){
  int t = threadIdx.x;  // 64 threads, nb <= 64
  int v = (t < nb) ? partial[t] : 0;
  int incl = v;
  #pragma unroll
  for (int d = 1; d < 64; d <<= 1){
    int u = __shfl_up(incl, d);
    if (t >= d) incl += u;
  }
  if (t < nb) partial[t] = incl - v;   // exclusive
  if (t == 63) rowptr[n] = incl;       // grand total
}

// fscan also emits dis[i] = rsqrt(deg+1)
__global__ __launch_bounds__(256)
void k_fscan(const int* __restrict__ cnt, const int* __restrict__ partial,
             int* __restrict__ rowptr, float* __restrict__ dis, int n){
  __shared__ int sh[256];
  int t = threadIdx.x;
  int base = blockIdx.x * 1024 + t * 4;
  int v0=0, v1=0, v2=0, v3=0;
  if (base + 3 < n){
    int4 v = *(const int4*)(cnt + base);
    v0=v.x; v1=v.y; v2=v.z; v3=v.w;
  } else {
    if (base   < n) v0 = cnt[base];
    if (base+1 < n) v1 = cnt[base+1];
    if (base+2 < n) v2 = cnt[base+2];
    if (base+3 < n) v3 = cnt[base+3];
  }
  int tsum = v0 + v1 + v2 + v3;
  sh[t] = tsum;
  __syncthreads();
  for (int off = 1; off < 256; off <<= 1){
    int u = (t >= off) ? sh[t - off] : 0;
    __syncthreads();
    sh[t] += u;
    __syncthreads();
  }
  int excl = sh[t] - tsum + partial[blockIdx.x];
  if (base   < n){ rowptr[base  ] = excl;             dis[base  ] = rsqrtf((float)v0 + 1.0f); }
  if (base+1 < n){ rowptr[base+1] = excl + v0;        dis[base+1] = rsqrtf((float)v1 + 1.0f); }
  if (base+2 < n){ rowptr[base+2] = excl + v0 + v1;   dis[base+2] = rsqrtf((float)v2 + 1.0f); }
  if (base+3 < n){ rowptr[base+3] = excl + v0+v1+v2;  dis[base+3] = rsqrtf((float)v3 + 1.0f); }
}

__global__ void k_fill(const int* __restrict__ ei, const int* __restrict__ rowptr,
                       int* __restrict__ fill, int* __restrict__ colidx, int E){
  int e = blockIdx.x * blockDim.x + threadIdx.x;
  if (e < E){
    int d = ei[E + e];
    int pos = rowptr[d] + atomicAdd(&fill[d], 1);
    colidx[pos] = ei[e];
  }
}

// Pack W [k][n] row-major f32 -> bf16 layout [n>>4][k>>3][n&15][k&7]
__global__ void k_pack(const float* __restrict__ W, unsigned short* __restrict__ Wp){
  int g = blockIdx.x * blockDim.x + threadIdx.x;   // 0..DIM*DIM-1
  int k = g >> 9, n = g & 511;
  int idx = ((n >> 4) << 13) + ((k >> 3) << 7) + ((n & 15) << 3) + (k & 7);
  Wp[idx] = f2b(W[g]);
}

// ---------------- GEMM: C = dis-scaled (A @ W), bf16 out ----------------
// Block 256 thr = 4 waves. Block tile 64(M) x 256(N); waves split N.
// Wave tile: 64M x 64N -> acc[4 m-subs][4 n-tiles] = 64 VGPR.
// A-frag reuse = 4, B-frag reuse = 4.
// grid = (ceil(Nr/64), 2): A logically streamed 2x (2nd pass L3-served).
// AF32: A is float32 (layer 1 reads x directly, converts in-register).
// D map: row = q*4 + r, col = l15   [m89-verified]
template<int AF32>
__global__ __launch_bounds__(256, 3)
void k_gemm(const void* __restrict__ Av, const unsigned short* __restrict__ Wp,
            const float* __restrict__ dis, unsigned short* __restrict__ C, int Nr)
{
  const int wv   = threadIdx.x >> 6;
  const int lane = threadIdx.x & 63;
  const int l15  = lane & 15;
  const int q    = lane >> 4;
  const int R0   = blockIdx.x * 64;                 // block's first row
  const int n0   = blockIdx.y * 256 + wv * 64;      // wave's col base

  size_t aoff[4];
  #pragma unroll
  for (int s = 0; s < 4; ++s){
    int ar = R0 + s * 16 + l15;
    if (ar >= Nr) ar = Nr - 1;
    aoff[s] = (size_t)ar * DIM + q * 8;
  }
  const unsigned short* __restrict__ Ab = (const unsigned short*)Av;
  const float*          __restrict__ Af = (const float*)Av;
  const unsigned short* __restrict__ bp = Wp + (size_t)(n0 >> 4) * 8192 + q * 128 + l15 * 8;

  floatx4 acc[4][4];
  #pragma unroll
  for (int s = 0; s < 4; ++s)
    #pragma unroll
    for (int nt = 0; nt < 4; ++nt)
      acc[s][nt] = (floatx4){0,0,0,0};

  #pragma unroll 4
  for (int ks = 0; ks < 16; ++ks){
    short8 a[4];
    if (AF32){
      #pragma unroll
      for (int s = 0; s < 4; ++s){
        float4 lo = *(const float4*)(Af + aoff[s] + ks * 32);
        float4 hi = *(const float4*)(Af + aoff[s] + ks * 32 + 4);
        short8 t;
        t[0] = (short)f2b(lo.x); t[1] = (short)f2b(lo.y);
        t[2] = (short)f2b(lo.z); t[3] = (short)f2b(lo.w);
        t[4] = (short)f2b(hi.x); t[5] = (short)f2b(hi.y);
        t[6] = (short)f2b(hi.z); t[7] = (short)f2b(hi.w);
        a[s] = t;
      }
    } else {
      #pragma unroll
      for (int s = 0; s < 4; ++s)
        a[s] = *(const short8*)(Ab + aoff[s] + ks * 32);
    }
    #pragma unroll
    for (int nt = 0; nt < 4; ++nt){
      short8 b = *(const short8*)(bp + nt * 8192 + ks * 512);
      acc[0][nt] = __builtin_amdgcn_mfma_f32_16x16x32_bf16(a[0], b, acc[0][nt], 0, 0, 0);
      acc[1][nt] = __builtin_amdgcn_mfma_f32_16x16x32_bf16(a[1], b, acc[1][nt], 0, 0, 0);
      acc[2][nt] = __builtin_amdgcn_mfma_f32_16x16x32_bf16(a[2], b, acc[2][nt], 0, 0, 0);
      acc[3][nt] = __builtin_amdgcn_mfma_f32_16x16x32_bf16(a[3], b, acc[3][nt], 0, 0, 0);
    }
  }

  #pragma unroll
  for (int s = 0; s < 4; ++s){
    #pragma unroll
    for (int r = 0; r < 4; ++r){
      int row = R0 + s * 16 + q * 4 + r;
      if (row < Nr){
        float ds = dis[row];
        size_t base = (size_t)row * DIM + n0 + l15;
        #pragma unroll
        for (int nt = 0; nt < 4; ++nt)
          C[base + nt * 16] = f2b(acc[s][nt][r] * ds);
      }
    }
  }
}

// ---------------- Aggregation: out_i = dis_i * (H[i] + sum_{s in N(i)} H[s]) + b ----
// One wave per node; lane holds 8 bf16 (16 B) of the 1 KB row. 4 nodes/block.
template<int RELU, int OUTBF16>
__global__ __launch_bounds__(256)
void k_agg(const unsigned short* __restrict__ H, const int* __restrict__ rowptr,
           const int* __restrict__ colidx, const float* __restrict__ dis,
           const float* __restrict__ bias, void* __restrict__ outp, int Nn)
{
  const int i = blockIdx.x * 4 + (threadIdx.x >> 6);
  if (i >= Nn) return;
  const int l = threadIdx.x & 63;
  const int f = l * 8;
  const float di = dis[i];

  float a0,a1,a2,a3,a4,a5,a6,a7;
  {
    uint4 u = *(const uint4*)(H + (size_t)i * DIM + f);
    a0 = blo(u.x); a1 = bhi(u.x); a2 = blo(u.y); a3 = bhi(u.y);
    a4 = blo(u.z); a5 = bhi(u.z); a6 = blo(u.w); a7 = bhi(u.w);
  }
  int e  = rowptr[i];
  const int r1 = rowptr[i + 1];
  for (; e + 1 < r1; e += 2){
    int s0 = colidx[e], s1 = colidx[e + 1];
    uint4 u = *(const uint4*)(H + (size_t)s0 * DIM + f);
    uint4 v = *(const uint4*)(H + (size_t)s1 * DIM + f);
    a0 += blo(u.x); a1 += bhi(u.x); a2 += blo(u.y); a3 += bhi(u.y);
    a4 += blo(u.z); a5 += bhi(u.z); a6 += blo(u.w); a7 += bhi(u.w);
    a0 += blo(v.x); a1 += bhi(v.x); a2 += blo(v.y); a3 += bhi(v.y);
    a4 += blo(v.z); a5 += bhi(v.z); a6 += blo(v.w); a7 += bhi(v.w);
  }
  if (e < r1){
    int s0 = colidx[e];
    uint4 u = *(const uint4*)(H + (size_t)s0 * DIM + f);
    a0 += blo(u.x); a1 += bhi(u.x); a2 += blo(u.y); a3 += bhi(u.y);
    a4 += blo(u.z); a5 += bhi(u.z); a6 += blo(u.w); a7 += bhi(u.w);
  }
  float4 b0 = *(const float4*)(bias + f);
  float4 b1 = *(const float4*)(bias + f + 4);
  a0 = a0 * di + b0.x; a1 = a1 * di + b0.y; a2 = a2 * di + b0.z; a3 = a3 * di + b0.w;
  a4 = a4 * di + b1.x; a5 = a5 * di + b1.y; a6 = a6 * di + b1.z; a7 = a7 * di + b1.w;
  if (RELU){
    a0 = fmaxf(a0, 0.f); a1 = fmaxf(a1, 0.f); a2 = fmaxf(a2, 0.f); a3 = fmaxf(a3, 0.f);
    a4 = fmaxf(a4, 0.f); a5 = fmaxf(a5, 0.f); a6 = fmaxf(a6, 0.f); a7 = fmaxf(a7, 0.f);
  }
  if (OUTBF16){
    uint4 o;
    o.x = (uint32_t)f2b(a0) | ((uint32_t)f2b(a1) << 16);
    o.y = (uint32_t)f2b(a2) | ((uint32_t)f2b(a3) << 16);
    o.z = (uint32_t)f2b(a4) | ((uint32_t)f2b(a5) << 16);
    o.w = (uint32_t)f2b(a6) | ((uint32_t)f2b(a7) << 16);
    ((uint4*)outp)[(size_t)i * 64 + l] = o;
  } else {
    float* op = (float*)outp + (size_t)i * DIM + f;
    float4 o0; o0.x = a0; o0.y = a1; o0.z = a2; o0.w = a3;
    float4 o1; o1.x = a4; o1.y = a5; o1.z = a6; o1.w = a7;
    *(float4*)op = o0;
    *(float4*)(op + 4) = o1;
  }
}

// ---------------- launch ----------------
extern "C" void kernel_launch(void* const* d_in, const int* in_sizes, int n_in,
                              void* d_out, int out_size, void* d_ws, size_t ws_size,
                              hipStream_t stream)
{
  const float* x  = (const float*)d_in[0];
  const int*   ei = (const int*)d_in[1];
  const float* W1 = (const float*)d_in[2];
  const float* b1 = (const float*)d_in[3];
  const float* W2 = (const float*)d_in[4];
  const float* b2 = (const float*)d_in[5];
  const int N = in_sizes[0] / DIM;
  const int E = in_sizes[1] / 2;

  char* p = (char*)d_ws;
  auto alloc = [&](size_t bytes) -> char* {
    char* r = p; p += (bytes + 255) & ~(size_t)255; return r;
  };
  unsigned short* xb   = (unsigned short*)alloc((size_t)N * DIM * 2);
  unsigned short* hb   = (unsigned short*)alloc((size_t)N * DIM * 2);
  unsigned short* W1p  = (unsigned short*)alloc((size_t)DIM * DIM * 2);
  unsigned short* W2p  = (unsigned short*)alloc((size_t)DIM * DIM * 2);
  float* dis    = (float*)alloc((size_t)N * 4);
  char*  cz     = alloc((size_t)N * 4);          // cnt
  char*  fz     = alloc((size_t)N * 4);          // fill (contiguous with cnt)
  int*   cnt    = (int*)cz;
  int*   fill   = (int*)fz;
  int*   rowptr = (int*)alloc((size_t)(N + 1) * 4);
  int*   colidx = (int*)alloc((size_t)E * 4);
  int*   partial= (int*)alloc(64 * 4);

  const int nsb = (N + 1023) / 1024;   // scan blocks (<=64)

  // zero cnt+fill in one async memset (they're contiguous in ws)
  hipMemsetAsync(cz, 0, (size_t)(fz - cz) + (size_t)N * 4, stream);

  // CSR + normalization
  k_count<<<(E + 255) / 256, 256, 0, stream>>>(ei, cnt, E);
  k_bsum<<<nsb, 256, 0, stream>>>(cnt, partial, N);
  k_pscan<<<1, 64, 0, stream>>>(partial, rowptr, nsb, N);
  k_fscan<<<nsb, 256, 0, stream>>>(cnt, partial, rowptr, dis, N);
  k_fill<<<(E + 255) / 256, 256, 0, stream>>>(ei, rowptr, fill, colidx, E);

  // weight prep
  k_pack<<<(DIM * DIM) / 256, 256, 0, stream>>>(W1, W1p);
  k_pack<<<(DIM * DIM) / 256, 256, 0, stream>>>(W2, W2p);

  dim3 gg((N + 63) / 64, DIM / 256);
  // layer 1: H1 = dis * (x @ W1)  (x read as f32, converted in-register)
  k_gemm<1><<<gg, 256, 0, stream>>>(x, W1p, dis, hb, N);
  k_agg<1, 1><<<(N + 3) / 4, 256, 0, stream>>>(hb, rowptr, colidx, dis, b1, xb, N);
  // layer 2: H2 = dis * (x2 @ W2); out f32
  k_gemm<0><<<gg, 256, 0, stream>>>(xb, W2p, dis, hb, N);
  k_agg<0, 0><<<(N + 3) / 4, 256, 0, stream>>>(hb, rowptr, colidx, dis, b2, d_out, N);
}

// Round 4
// 391.043 us; speedup vs baseline: 1.2326x; 1.2326x over previous
//
#include <hip/hip_runtime.h>
#include <stdint.h>

#define DIM 512

typedef short short8 __attribute__((ext_vector_type(8)));
typedef float floatx4 __attribute__((ext_vector_type(4)));

// f32 -> bf16 round-to-nearest-even
__device__ __forceinline__ unsigned short f2b(float x){
  uint32_t u = __float_as_uint(x);
  u += 0x7FFFu + ((u >> 16) & 1u);
  return (unsigned short)(u >> 16);
}
__device__ __forceinline__ float blo(uint32_t u){ return __uint_as_float(u << 16); }
__device__ __forceinline__ float bhi(uint32_t u){ return __uint_as_float(u & 0xFFFF0000u); }

// async global->LDS, 16 B per lane. LDS dest = wave-uniform base + lane*16.
__device__ __forceinline__ void gld_lds16(const void* g, void* l){
  __builtin_amdgcn_global_load_lds(
      (const __attribute__((address_space(1))) void*)g,
      (__attribute__((address_space(3))) void*)l, 16, 0, 0);
}

// ---------------- CSR build ----------------
__global__ void k_count(const int* __restrict__ ei, int* __restrict__ cnt, int E){
  int e = blockIdx.x * blockDim.x + threadIdx.x;
  if (e < E) atomicAdd(&cnt[ei[E + e]], 1);
}

__global__ __launch_bounds__(256)
void k_bsum(const int* __restrict__ cnt, int* __restrict__ partial, int n){
  __shared__ int sh[4];
  int t = threadIdx.x;
  int base = blockIdx.x * 1024 + t * 4;
  int s = 0;
  if (base + 3 < n){
    int4 v = *(const int4*)(cnt + base);
    s = v.x + v.y + v.z + v.w;
  } else {
    for (int j = 0; j < 4; ++j) if (base + j < n) s += cnt[base + j];
  }
  for (int d = 32; d; d >>= 1) s += __shfl_down(s, d);
  if ((t & 63) == 0) sh[t >> 6] = s;
  __syncthreads();
  if (t == 0) partial[blockIdx.x] = sh[0] + sh[1] + sh[2] + sh[3];
}

__global__ void k_pscan(int* __restrict__ partial, int* __restrict__ rowptr, int nb, int n){
  int t = threadIdx.x;  // 64 threads, nb <= 64
  int v = (t < nb) ? partial[t] : 0;
  int incl = v;
  #pragma unroll
  for (int d = 1; d < 64; d <<= 1){
    int u = __shfl_up(incl, d);
    if (t >= d) incl += u;
  }
  if (t < nb) partial[t] = incl - v;   // exclusive
  if (t == 63) rowptr[n] = incl;       // grand total
}

// fscan also emits dis[i] = rsqrt(deg+1)
__global__ __launch_bounds__(256)
void k_fscan(const int* __restrict__ cnt, const int* __restrict__ partial,
             int* __restrict__ rowptr, float* __restrict__ dis, int n){
  __shared__ int sh[256];
  int t = threadIdx.x;
  int base = blockIdx.x * 1024 + t * 4;
  int v0=0, v1=0, v2=0, v3=0;
  if (base + 3 < n){
    int4 v = *(const int4*)(cnt + base);
    v0=v.x; v1=v.y; v2=v.z; v3=v.w;
  } else {
    if (base   < n) v0 = cnt[base];
    if (base+1 < n) v1 = cnt[base+1];
    if (base+2 < n) v2 = cnt[base+2];
    if (base+3 < n) v3 = cnt[base+3];
  }
  int tsum = v0 + v1 + v2 + v3;
  sh[t] = tsum;
  __syncthreads();
  for (int off = 1; off < 256; off <<= 1){
    int u = (t >= off) ? sh[t - off] : 0;
    __syncthreads();
    sh[t] += u;
    __syncthreads();
  }
  int excl = sh[t] - tsum + partial[blockIdx.x];
  if (base   < n){ rowptr[base  ] = excl;             dis[base  ] = rsqrtf((float)v0 + 1.0f); }
  if (base+1 < n){ rowptr[base+1] = excl + v0;        dis[base+1] = rsqrtf((float)v1 + 1.0f); }
  if (base+2 < n){ rowptr[base+2] = excl + v0 + v1;   dis[base+2] = rsqrtf((float)v2 + 1.0f); }
  if (base+3 < n){ rowptr[base+3] = excl + v0+v1+v2;  dis[base+3] = rsqrtf((float)v3 + 1.0f); }
}

__global__ void k_fill(const int* __restrict__ ei, const int* __restrict__ rowptr,
                       int* __restrict__ fill, int* __restrict__ colidx, int E){
  int e = blockIdx.x * blockDim.x + threadIdx.x;
  if (e < E){
    int d = ei[E + e];
    int pos = rowptr[d] + atomicAdd(&fill[d], 1);
    colidx[pos] = ei[e];
  }
}

// ---------------- dtype prep ----------------
__global__ void k_cvt(const float* __restrict__ x, unsigned short* __restrict__ xb, long n4){
  long i = blockIdx.x * (long)blockDim.x + threadIdx.x;
  if (i < n4){
    float4 v = ((const float4*)x)[i];
    ushort4 o;
    o.x = f2b(v.x); o.y = f2b(v.y); o.z = f2b(v.z); o.w = f2b(v.w);
    ((ushort4*)xb)[i] = o;
  }
}

// Pack W [k][n] row-major f32 -> bf16 layout [n>>4][k>>3][n&15][k&7]
__global__ void k_pack(const float* __restrict__ W, unsigned short* __restrict__ Wp){
  int g = blockIdx.x * blockDim.x + threadIdx.x;   // 0..DIM*DIM-1
  int k = g >> 9, n = g & 511;
  int idx = ((n >> 4) << 13) + ((k >> 3) << 7) + ((n & 15) << 3) + (k & 7);
  Wp[idx] = f2b(W[g]);
}

// ---------------- GEMM: C = dis-scaled (A @ W), bf16 in/out, LDS-staged ----------------
// m97 structure. Block 256 thr = 4 waves. Tile 128M x 128N, BK=64, 8 K-steps.
// LDS 32KB single-buffered: A[128][64] bf16 (16KB, XOR-swizzled chunks), B 16KB
// (packed frag-contiguous). Per BK-step per wave: 16 ds_read_b128 + 32 MFMA.
// Wave w: m-half h=w&1 (64 rows), n-half v=w>>1 (64 cols). acc 4x4x4 = 64 regs.
// A-swizzle: LDS[row][chunk] holds global chunk (chunk ^ (row&7)); applied on the
// GLOBAL address at staging (LDS side must stay lane-linear for global_load_lds).
// D map: row = q*4 + r, col = l15   [m89-verified]
__global__ __launch_bounds__(256, 3)
void k_gemm(const unsigned short* __restrict__ A, const unsigned short* __restrict__ Wp,
            const float* __restrict__ dis, unsigned short* __restrict__ C, int Nr)
{
  __shared__ unsigned short smem[16384];   // A: [0,8192) elems, B: [8192,16384)
  const int tid  = threadIdx.x;
  const int w    = tid >> 6;
  const int lane = tid & 63;
  const int l15  = lane & 15;
  const int q    = lane >> 4;
  const int R0   = blockIdx.x * 128;
  const int n0   = blockIdx.y * 128;
  const int h    = w & 1;
  const int v    = w >> 1;

  // staging lane constants
  const int srow   = lane >> 3;                      // row within an 8-row issue
  const int schunk = (lane & 7) ^ (srow & 7);        // swizzled global chunk
  // compute lane constant
  const int X = l15 & 7;

  int garow[4];
  #pragma unroll
  for (int j = 0; j < 4; ++j){
    int gr = R0 + (w * 4 + j) * 8 + srow;
    if (gr >= Nr) gr = Nr - 1;
    garow[j] = gr;
  }
  const size_t wpbase = (size_t)(n0 >> 4) * 8192;    // elem offset of first n-group

  floatx4 acc[4][4];
  #pragma unroll
  for (int s = 0; s < 4; ++s)
    #pragma unroll
    for (int nt = 0; nt < 4; ++nt)
      acc[s][nt] = (floatx4){0,0,0,0};

  for (int t = 0; t < 8; ++t){
    if (t) __syncthreads();
    #pragma unroll
    for (int j = 0; j < 4; ++j){
      const int ia = w * 4 + j;                      // 0..15
      // A: rows ia*8..ia*8+7, k-bytes [t*128, t*128+128), swizzled chunk
      gld_lds16(A + (size_t)garow[j] * DIM + t * 64 + schunk * 8, &smem[ia * 512]);
      // B: n-group ia>>1, half ia&1, 1KB contiguous in packed Wp
      gld_lds16(Wp + wpbase + (size_t)(ia >> 1) * 8192 + t * 1024 + (ia & 1) * 512 + lane * 8,
                &smem[8192 + ia * 512]);
    }
    __syncthreads();   // drains vmcnt(0) before barrier -> LDS valid

    #pragma unroll
    for (int ksl = 0; ksl < 2; ++ksl){
      short8 a[4], b[4];
      #pragma unroll
      for (int s = 0; s < 4; ++s){
        const int rho = h * 64 + s * 16 + l15;
        const int cc  = (ksl * 4 + q) ^ X;
        a[s] = *(const short8*)&smem[rho * 64 + cc * 8];
      }
      #pragma unroll
      for (int nt = 0; nt < 4; ++nt)
        b[nt] = *(const short8*)&smem[8192 + (v * 4 + nt) * 1024 + ksl * 512 + q * 128 + l15 * 8];
      #pragma unroll
      for (int nt = 0; nt < 4; ++nt){
        acc[0][nt] = __builtin_amdgcn_mfma_f32_16x16x32_bf16(a[0], b[nt], acc[0][nt], 0, 0, 0);
        acc[1][nt] = __builtin_amdgcn_mfma_f32_16x16x32_bf16(a[1], b[nt], acc[1][nt], 0, 0, 0);
        acc[2][nt] = __builtin_amdgcn_mfma_f32_16x16x32_bf16(a[2], b[nt], acc[2][nt], 0, 0, 0);
        acc[3][nt] = __builtin_amdgcn_mfma_f32_16x16x32_bf16(a[3], b[nt], acc[3][nt], 0, 0, 0);
      }
    }
  }

  #pragma unroll
  for (int s = 0; s < 4; ++s){
    #pragma unroll
    for (int r = 0; r < 4; ++r){
      const int row = R0 + h * 64 + s * 16 + q * 4 + r;
      if (row < Nr){
        const float ds = dis[row];
        size_t base = (size_t)row * DIM + n0 + v * 64 + l15;
        #pragma unroll
        for (int nt = 0; nt < 4; ++nt)
          C[base + nt * 16] = f2b(acc[s][nt][r] * ds);
      }
    }
  }
}

// ---------------- Aggregation: out_i = dis_i * (H[i] + sum_{s in N(i)} H[s]) + b ----
// One wave per node; lane holds 8 bf16 (16 B) of the 1 KB row. 4 nodes/block.
template<int RELU, int OUTBF16>
__global__ __launch_bounds__(256)
void k_agg(const unsigned short* __restrict__ H, const int* __restrict__ rowptr,
           const int* __restrict__ colidx, const float* __restrict__ dis,
           const float* __restrict__ bias, void* __restrict__ outp, int Nn)
{
  const int i = blockIdx.x * 4 + (threadIdx.x >> 6);
  if (i >= Nn) return;
  const int l = threadIdx.x & 63;
  const int f = l * 8;
  const float di = dis[i];

  float a0,a1,a2,a3,a4,a5,a6,a7;
  {
    uint4 u = *(const uint4*)(H + (size_t)i * DIM + f);
    a0 = blo(u.x); a1 = bhi(u.x); a2 = blo(u.y); a3 = bhi(u.y);
    a4 = blo(u.z); a5 = bhi(u.z); a6 = blo(u.w); a7 = bhi(u.w);
  }
  int e  = rowptr[i];
  const int r1 = rowptr[i + 1];
  for (; e + 1 < r1; e += 2){
    int s0 = colidx[e], s1 = colidx[e + 1];
    uint4 u = *(const uint4*)(H + (size_t)s0 * DIM + f);
    uint4 v = *(const uint4*)(H + (size_t)s1 * DIM + f);
    a0 += blo(u.x); a1 += bhi(u.x); a2 += blo(u.y); a3 += bhi(u.y);
    a4 += blo(u.z); a5 += bhi(u.z); a6 += blo(u.w); a7 += bhi(u.w);
    a0 += blo(v.x); a1 += bhi(v.x); a2 += blo(v.y); a3 += bhi(v.y);
    a4 += blo(v.z); a5 += bhi(v.z); a6 += blo(v.w); a7 += bhi(v.w);
  }
  if (e < r1){
    int s0 = colidx[e];
    uint4 u = *(const uint4*)(H + (size_t)s0 * DIM + f);
    a0 += blo(u.x); a1 += bhi(u.x); a2 += blo(u.y); a3 += bhi(u.y);
    a4 += blo(u.z); a5 += bhi(u.z); a6 += blo(u.w); a7 += bhi(u.w);
  }
  float4 b0 = *(const float4*)(bias + f);
  float4 b1 = *(const float4*)(bias + f + 4);
  a0 = a0 * di + b0.x; a1 = a1 * di + b0.y; a2 = a2 * di + b0.z; a3 = a3 * di + b0.w;
  a4 = a4 * di + b1.x; a5 = a5 * di + b1.y; a6 = a6 * di + b1.z; a7 = a7 * di + b1.w;
  if (RELU){
    a0 = fmaxf(a0, 0.f); a1 = fmaxf(a1, 0.f); a2 = fmaxf(a2, 0.f); a3 = fmaxf(a3, 0.f);
    a4 = fmaxf(a4, 0.f); a5 = fmaxf(a5, 0.f); a6 = fmaxf(a6, 0.f); a7 = fmaxf(a7, 0.f);
  }
  if (OUTBF16){
    uint4 o;
    o.x = (uint32_t)f2b(a0) | ((uint32_t)f2b(a1) << 16);
    o.y = (uint32_t)f2b(a2) | ((uint32_t)f2b(a3) << 16);
    o.z = (uint32_t)f2b(a4) | ((uint32_t)f2b(a5) << 16);
    o.w = (uint32_t)f2b(a6) | ((uint32_t)f2b(a7) << 16);
    ((uint4*)outp)[(size_t)i * 64 + l] = o;
  } else {
    float* op = (float*)outp + (size_t)i * DIM + f;
    float4 o0; o0.x = a0; o0.y = a1; o0.z = a2; o0.w = a3;
    float4 o1; o1.x = a4; o1.y = a5; o1.z = a6; o1.w = a7;
    *(float4*)op = o0;
    *(float4*)(op + 4) = o1;
  }
}

// ---------------- launch ----------------
extern "C" void kernel_launch(void* const* d_in, const int* in_sizes, int n_in,
                              void* d_out, int out_size, void* d_ws, size_t ws_size,
                              hipStream_t stream)
{
  const float* x  = (const float*)d_in[0];
  const int*   ei = (const int*)d_in[1];
  const float* W1 = (const float*)d_in[2];
  const float* b1 = (const float*)d_in[3];
  const float* W2 = (const float*)d_in[4];
  const float* b2 = (const float*)d_in[5];
  const int N = in_sizes[0] / DIM;
  const int E = in_sizes[1] / 2;

  char* p = (char*)d_ws;
  auto alloc = [&](size_t bytes) -> char* {
    char* r = p; p += (bytes + 255) & ~(size_t)255; return r;
  };
  unsigned short* xb   = (unsigned short*)alloc((size_t)N * DIM * 2);
  unsigned short* hb   = (unsigned short*)alloc((size_t)N * DIM * 2);
  unsigned short* W1p  = (unsigned short*)alloc((size_t)DIM * DIM * 2);
  unsigned short* W2p  = (unsigned short*)alloc((size_t)DIM * DIM * 2);
  float* dis    = (float*)alloc((size_t)N * 4);
  char*  cz     = alloc((size_t)N * 4);          // cnt
  char*  fz     = alloc((size_t)N * 4);          // fill (contiguous with cnt)
  int*   cnt    = (int*)cz;
  int*   fill   = (int*)fz;
  int*   rowptr = (int*)alloc((size_t)(N + 1) * 4);
  int*   colidx = (int*)alloc((size_t)E * 4);
  int*   partial= (int*)alloc(64 * 4);

  const int nsb = (N + 1023) / 1024;   // scan blocks (<=64)

  // zero cnt+fill in one async memset (contiguous in ws)
  hipMemsetAsync(cz, 0, (size_t)(fz - cz) + (size_t)N * 4, stream);

  // CSR + normalization
  k_count<<<(E + 255) / 256, 256, 0, stream>>>(ei, cnt, E);
  k_bsum<<<nsb, 256, 0, stream>>>(cnt, partial, N);
  k_pscan<<<1, 64, 0, stream>>>(partial, rowptr, nsb, N);
  k_fscan<<<nsb, 256, 0, stream>>>(cnt, partial, rowptr, dis, N);
  k_fill<<<(E + 255) / 256, 256, 0, stream>>>(ei, rowptr, fill, colidx, E);

  // dtype prep
  long n4 = (long)N * DIM / 4;
  k_cvt<<<(int)((n4 + 255) / 256), 256, 0, stream>>>(x, xb, n4);
  k_pack<<<(DIM * DIM) / 256, 256, 0, stream>>>(W1, W1p);
  k_pack<<<(DIM * DIM) / 256, 256, 0, stream>>>(W2, W2p);

  dim3 gg((N + 127) / 128, DIM / 128);
  // layer 1: H1 = dis * (x @ W1); x2 = relu(dis * agg(H1) + b1) in bf16 (into xb)
  k_gemm<<<gg, 256, 0, stream>>>(xb, W1p, dis, hb, N);
  k_agg<1, 1><<<(N + 3) / 4, 256, 0, stream>>>(hb, rowptr, colidx, dis, b1, xb, N);
  // layer 2: H2 = dis * (x2 @ W2); out f32
  k_gemm<<<gg, 256, 0, stream>>>(xb, W2p, dis, hb, N);
  k_agg<0, 0><<<(N + 3) / 4, 256, 0, stream>>>(hb, rowptr, colidx, dis, b2, d_out, N);
}